// Round 12
// baseline (424.868 us; speedup 1.0000x reference)
//
#include <hip/hip_runtime.h>
#include <hip/hip_bf16.h>

// LocalAggregation: B=8, N=2048, K=32, D=64, C1=64, C2=128, R=0.15, EPS=1e-5
// f32 storage, bf16-ified values.
// Factored stats1 (validated R7-R11):
//   h1[row,c] = g[m,c] + dx*wx[c]+dy*wy[c]+dz*wz[c],  g = feat @ W1[3:]
//   sum1[c]   = SUM_m cnt[m] g[m,c] + wx M1x + wy M1y + wz M1z
//   sumsq1[c] = SUM_m cnt g^2 + 2(wx A3x + wy A3y + wz A3z) + quadratic moments
// R12: kP v5 — u32/i32 fixed-point (2^-21) LDS accumulators (32 KB, 1-bank
//   atomics; u64 was 2-bank: 200K conflicts), 512 blocks x 32-site slices
//   (2 blocks/CU chip-wide; 128 blocks left half the CUs idle), flush =
//   native global integer atomicAdd with zero-skip. kR deleted; kB converts
//   on read. kD remains R8 ((256,2); (256,4) spilled).
// gamma2>0 => max-pool commutes with bn2+relu (k45).

#define BB 8
#define NN 2048
#define KK 32
#define DD 64
#define CC1 64
#define CC2 128
#define TOTROWS (BB*NN*KK) // 524288
#define SITES (BB*NN)      // 16384

typedef __bf16 bf16x8 __attribute__((ext_vector_type(8)));
typedef float  f32x4  __attribute__((ext_vector_type(4)));

__device__ __forceinline__ void lds_add(float* p, float v) {
  __hip_atomic_fetch_add(p, v, __ATOMIC_RELAXED, __HIP_MEMORY_SCOPE_WORKGROUP);
}

// ---------------- K1: ball query, ballot compaction ----------------
// 512 blocks x 256 thr; block = (batch, 32-query group), wave = 8 queries.
__global__ __launch_bounds__(256) void k1_ball(const float* __restrict__ pos,
                                               int* __restrict__ idx)
{
  __shared__ float4 P[NN];  // 32 KB: x,y,z,S
  const int b = blockIdx.x >> 6;
  const int qbase = (blockIdx.x & 63) * 32;
  for (int i = threadIdx.x; i < NN; i += 256) {
    const float* p = pos + ((size_t)b*NN + i)*3;
    float x = p[0], y = p[1], z = p[2];
    float s = __fadd_rn(__fadd_rn(__fmul_rn(x,x), __fmul_rn(y,y)), __fmul_rn(z,z));
    P[i] = make_float4(x, y, z, s);
  }
  __syncthreads();
  const int wave = threadIdx.x >> 6, lane = threadIdx.x & 63;
  const float R2 = (float)(0.15 * 0.15);
  const unsigned long long lt = (lane == 63) ? 0x7fffffffffffffffull
                                             : ((1ull << lane) - 1ull);
  for (int qi = wave; qi < 32; qi += 4) {
    const int q = qbase + qi;
    const float4 Q = P[q];
    int* ip = idx + ((size_t)b*NN + q)*KK;
    int cnt = 0, first = -1;
    for (int step = 0; step < 32; ++step) {
      float4 p = P[step*64 + lane];
      float d = __fmul_rn(Q.x, p.x);
      d = fmaf(Q.y, p.y, d);
      d = fmaf(Q.z, p.z, d);
      float sq = __fsub_rn(__fadd_rn(Q.w, p.w), __fmul_rn(2.0f, d));
      bool in = !(sq > R2);
      unsigned long long mask = __ballot(in);
      if (first < 0 && mask) first = step*64 + (int)__builtin_ctzll(mask);
      int dst = cnt + (int)__popcll(mask & lt);
      if (in && dst < KK) ip[dst] = step*64 + lane;
      cnt += (int)__popcll(mask);
      if (cnt >= KK) break;
    }
    if (lane >= cnt && lane < KK) ip[lane] = first;  // cnt>=1 (self in ball)
  }
}

// ---------------- KP v5: per-m scatter, u32 LDS + global int atomics ----------------
// 512 blocks x 256 thr; block = (batch, 32-site slice); thread = (site, k/4).
// Fixed-point 2^-21 for DX/DY/DZ. Padding aggregated per thread.
__global__ __launch_bounds__(256) void kP_scatter(
    const float* __restrict__ pos, const int* __restrict__ idx,
    unsigned int* __restrict__ Gc, int* __restrict__ Gx,
    int* __restrict__ Gy, int* __restrict__ Gz,
    float* __restrict__ mom)
{
  __shared__ unsigned int Sc[NN];         // 8 KB
  __shared__ int Sx[NN], Sy[NN], Sz[NN];  // 24 KB
  const int b = blockIdx.x >> 6;          // 64 blocks per batch
  const int slice = blockIdx.x & 63;      // 32 sites each
  for (int i = threadIdx.x; i < NN; i += 256) {
    Sc[i] = 0u; Sx[i] = 0; Sy[i] = 0; Sz[i] = 0;
  }
  __syncthreads();
  const float* pb = pos + (size_t)b*NN*3;
  const int sl = threadIdx.x >> 3;        // site-local 0..31
  const int kg = threadIdx.x & 7;         // 4 k's each
  const int site = slice*32 + sl;
  const int* ip = idx + ((size_t)(b*NN + site))*KK;
  const int ip0 = ip[0];
  const float cx = pb[site*3], cy = pb[site*3+1], cz = pb[site*3+2];
  const float FS = 2097152.0f;            // 2^21
  float m1x=0.f,m1y=0.f,m1z=0.f,mxx=0.f,myy=0.f,mzz=0.f,mxy=0.f,mxz=0.f,myz=0.f;
  int wt = 0;
  #pragma unroll
  for (int j = 0; j < 4; ++j) {
    const int k = kg*4 + j;
    const int m = ip[k];
    float dx = pb[m*3  ] - cx;
    float dy = pb[m*3+1] - cy;
    float dz = pb[m*3+2] - cz;
    if (k > 0 && m == ip0) {
      ++wt;                               // padding: aggregate
    } else {
      atomicAdd(&Sc[m], 1u);              // ds_add_u32, single bank
      atomicAdd((unsigned int*)&Sx[m], (unsigned int)__float2int_rn(dx*FS));
      atomicAdd((unsigned int*)&Sy[m], (unsigned int)__float2int_rn(dy*FS));
      atomicAdd((unsigned int*)&Sz[m], (unsigned int)__float2int_rn(dz*FS));
    }
    m1x += dx; m1y += dy; m1z += dz;      // moments include padding rows
    mxx = fmaf(dx,dx,mxx); myy = fmaf(dy,dy,myy); mzz = fmaf(dz,dz,mzz);
    mxy = fmaf(dx,dy,mxy); mxz = fmaf(dx,dz,mxz); myz = fmaf(dy,dz,myz);
  }
  if (wt > 0) {
    float dx0 = pb[ip0*3  ] - cx;
    float dy0 = pb[ip0*3+1] - cy;
    float dz0 = pb[ip0*3+2] - cz;
    atomicAdd(&Sc[ip0], (unsigned int)wt);
    atomicAdd((unsigned int*)&Sx[ip0], (unsigned int)(wt*__float2int_rn(dx0*FS)));
    atomicAdd((unsigned int*)&Sy[ip0], (unsigned int)(wt*__float2int_rn(dy0*FS)));
    atomicAdd((unsigned int*)&Sz[ip0], (unsigned int)(wt*__float2int_rn(dz0*FS)));
  }
  __syncthreads();
  for (int i = threadIdx.x; i < NN; i += 256) {
    unsigned int c = Sc[i];
    if (c | (unsigned int)Sx[i] | (unsigned int)Sy[i] | (unsigned int)Sz[i]) {
      atomicAdd(&Gc[b*NN + i], c);                         // native int atomics
      atomicAdd((unsigned int*)&Gx[b*NN + i], (unsigned int)Sx[i]);
      atomicAdd((unsigned int*)&Gy[b*NN + i], (unsigned int)Sy[i]);
      atomicAdd((unsigned int*)&Gz[b*NN + i], (unsigned int)Sz[i]);
    }
  }
  const int lane = threadIdx.x & 63;
  float vals[9] = {m1x,m1y,m1z,mxx,myy,mzz,mxy,mxz,myz};
  #pragma unroll
  for (int i = 0; i < 9; ++i) {
    float v = vals[i];
    #pragma unroll
    for (int s = 1; s < 64; s <<= 1) v += __shfl_xor(v, s, 64);
    if (lane == 0) unsafeAtomicAdd(&mom[i], v);
  }
}

// ---------------- KB: g = feat @ W1[3:] via MFMA, fused A-sums ----------------
// 128 blocks x 256 thr -> 512 waves x 2 M-tiles (16 rows each).
// A layout: [0:64) Sum cnt*g, [64:128) Sum cnt*g^2, [128:192) Sum g*DX,
//           [192:256) Sum g*DY, [256:320) Sum g*DZ
__global__ __launch_bounds__(256) void kB_g(const float* __restrict__ feat,
                                            const float* __restrict__ W1,
                                            const unsigned int* __restrict__ Gc,
                                            const int* __restrict__ Gx,
                                            const int* __restrict__ Gy,
                                            const int* __restrict__ Gz,
                                            float* __restrict__ g,
                                            float* __restrict__ A)
{
  __shared__ float red[320];
  for (int i = threadIdx.x; i < 320; i += 256) red[i] = 0.f;
  __syncthreads();
  const int lane = threadIdx.x & 63;
  const int quad = lane >> 4;
  const int col  = lane & 15;
  const int gw = (blockIdx.x*256 + threadIdx.x) >> 6;   // 0..511
  const float IS = 4.76837158203125e-7f;  // 2^-21

  bf16x8 Bf[2][4];
  #pragma unroll
  for (int kt = 0; kt < 2; ++kt)
    #pragma unroll
    for (int nt = 0; nt < 4; ++nt) {
      bf16x8 v;
      #pragma unroll
      for (int j = 0; j < 8; ++j)
        v[j] = (__bf16)W1[(3 + kt*32 + quad*8 + j)*CC1 + nt*16 + col];
      Bf[kt][nt] = v;
    }
  float a1[4], a2[4], a3[4], a4[4], a5[4];
  #pragma unroll
  for (int nt = 0; nt < 4; ++nt) { a1[nt]=0.f; a2[nt]=0.f; a3[nt]=0.f; a4[nt]=0.f; a5[nt]=0.f; }

  for (int t = 0; t < 2; ++t) {
    const int row0 = (gw*2 + t) * 16;
    bf16x8 Af[2];
    #pragma unroll
    for (int kt = 0; kt < 2; ++kt) {
      const float4* fp =
        (const float4*)(feat + (size_t)(row0 + col)*DD + kt*32 + quad*8);
      float4 f0 = fp[0], f1 = fp[1];
      float fv[8] = {f0.x,f0.y,f0.z,f0.w,f1.x,f1.y,f1.z,f1.w};
      bf16x8 v;
      #pragma unroll
      for (int j = 0; j < 8; ++j) v[j] = (__bf16)fv[j];
      Af[kt] = v;
    }
    float cw[4], dxw[4], dyw[4], dzw[4];
    #pragma unroll
    for (int r = 0; r < 4; ++r) {
      int row = row0 + quad*4 + r;
      cw[r]  = (float)Gc[row];
      dxw[r] = (float)Gx[row] * IS;
      dyw[r] = (float)Gy[row] * IS;
      dzw[r] = (float)Gz[row] * IS;
    }
    #pragma unroll
    for (int nt = 0; nt < 4; ++nt) {
      f32x4 a = {0.f, 0.f, 0.f, 0.f};
      a = __builtin_amdgcn_mfma_f32_16x16x32_bf16(Af[0], Bf[0][nt], a, 0, 0, 0);
      a = __builtin_amdgcn_mfma_f32_16x16x32_bf16(Af[1], Bf[1][nt], a, 0, 0, 0);
      #pragma unroll
      for (int r = 0; r < 4; ++r) {
        float v = a[r];
        g[(size_t)(row0 + quad*4 + r)*CC1 + nt*16 + col] = v;
        float cv = cw[r]*v;
        a1[nt] += cv; a2[nt] = fmaf(cv, v, a2[nt]);
        a3[nt] = fmaf(dxw[r], v, a3[nt]);
        a4[nt] = fmaf(dyw[r], v, a4[nt]);
        a5[nt] = fmaf(dzw[r], v, a5[nt]);
      }
    }
  }
  #pragma unroll
  for (int nt = 0; nt < 4; ++nt) {
    float v1=a1[nt], v2=a2[nt], v3=a3[nt], v4=a4[nt], v5=a5[nt];
    v1 += __shfl_xor(v1,16,64); v1 += __shfl_xor(v1,32,64);
    v2 += __shfl_xor(v2,16,64); v2 += __shfl_xor(v2,32,64);
    v3 += __shfl_xor(v3,16,64); v3 += __shfl_xor(v3,32,64);
    v4 += __shfl_xor(v4,16,64); v4 += __shfl_xor(v4,32,64);
    v5 += __shfl_xor(v5,16,64); v5 += __shfl_xor(v5,32,64);
    if (quad == 0) {
      int ch = nt*16 + col;
      lds_add(&red[ch], v1);
      lds_add(&red[64+ch], v2);
      lds_add(&red[128+ch], v3);
      lds_add(&red[192+ch], v4);
      lds_add(&red[256+ch], v5);
    }
  }
  __syncthreads();
  for (int i = threadIdx.x; i < 320; i += 256) unsafeAtomicAdd(&A[i], red[i]);
}

// ---------------- KS: assemble stats1 -> sc1, sh1, W1s ----------------
__global__ __launch_bounds__(256) void kS_fold(
    const float* __restrict__ W1, const float* __restrict__ gamma1,
    const float* __restrict__ beta1, const float* __restrict__ A,
    const float* __restrict__ mom,
    float* __restrict__ sc1, float* __restrict__ sh1, float* __restrict__ W1s)
{
  int c = threadIdx.x;
  if (c >= CC1) return;
  float wx = W1[c], wy = W1[CC1+c], wz = W1[2*CC1+c];
  float A1 = A[c], A2 = A[64+c], A3x = A[128+c], A3y = A[192+c], A3z = A[256+c];
  float sum1 = A1 + wx*mom[0] + wy*mom[1] + wz*mom[2];
  float ss = A2 + 2.f*(wx*A3x + wy*A3y + wz*A3z)
           + wx*wx*mom[3] + wy*wy*mom[4] + wz*wz*mom[5]
           + 2.f*(wx*wy*mom[6] + wx*wz*mom[7] + wy*wz*mom[8]);
  const float invN = 1.0f / (float)TOTROWS;
  float mean = sum1 * invN;
  float var  = ss * invN - mean*mean;
  float sc = rsqrtf(var + 1e-5f) * gamma1[c];
  float sh = beta1[c] - mean * sc;
  sc1[c] = sc; sh1[c] = sh;
  W1s[c] = wx*sc; W1s[64+c] = wy*sc; W1s[128+c] = wz*sc;
}

// ---------------- KD: MFMA main pass (BN1 inline) — R8 version ----------------
// 1024 blocks -> 4096 waves x 4 sites. Per site A1(32x64 bf16) @ W2(64x128).
// a = relu(g*sc + dx*wxs + dy*wys + dz*wzs + sh).
__global__ __launch_bounds__(256, 2) void kD_mfma(
    const float* __restrict__ pos, const int* __restrict__ idx,
    const float* __restrict__ g, const float* __restrict__ sc1,
    const float* __restrict__ sh1, const float* __restrict__ W1s,
    const float* __restrict__ W2,
    float* __restrict__ stats2, float* __restrict__ out_nf)
{
  __shared__ float red2[256];
  red2[threadIdx.x] = 0.f;
  __syncthreads();
  const int lane = threadIdx.x & 63;
  const int quad = lane >> 4;
  const int col  = lane & 15;
  const int gw = (blockIdx.x*256 + threadIdx.x) >> 6;

  bf16x8 Bf[2][8];
  #pragma unroll
  for (int kt = 0; kt < 2; ++kt)
    #pragma unroll
    for (int nt = 0; nt < 8; ++nt) {
      bf16x8 v;
      #pragma unroll
      for (int j = 0; j < 8; ++j)
        v[j] = (__bf16)W2[(kt*32 + quad*8 + j)*CC2 + nt*16 + col];
      Bf[kt][nt] = v;
    }
  float wxs[2][8], wys[2][8], wzs[2][8], scj[2][8], shj[2][8];
  #pragma unroll
  for (int kt = 0; kt < 2; ++kt)
    #pragma unroll
    for (int j = 0; j < 8; ++j) {
      int c = kt*32 + quad*8 + j;
      wxs[kt][j] = W1s[c]; wys[kt][j] = W1s[64+c]; wzs[kt][j] = W1s[128+c];
      scj[kt][j] = sc1[c]; shj[kt][j] = sh1[c];
    }
  float ssum[8], ssq[8];
  #pragma unroll
  for (int nt = 0; nt < 8; ++nt) { ssum[nt] = 0.f; ssq[nt] = 0.f; }

  for (int si = 0; si < 4; ++si) {
    const int site = gw*4 + si;
    const int b = site >> 11;
    const float* pc = pos + (size_t)site*3;
    const float cx = pc[0], cy = pc[1], cz = pc[2];
    int mm[2]; float dx[2], dy[2], dz[2];
    #pragma unroll
    for (int mt = 0; mt < 2; ++mt) {
      mm[mt] = idx[site*KK + mt*16 + col];
      const float* pm = pos + ((size_t)b*NN + mm[mt])*3;
      dx[mt] = pm[0]-cx; dy[mt] = pm[1]-cy; dz[mt] = pm[2]-cz;
    }
    bf16x8 Af[2][2];
    #pragma unroll
    for (int mt = 0; mt < 2; ++mt)
      #pragma unroll
      for (int kt = 0; kt < 2; ++kt) {
        const float4* gp =
          (const float4*)(g + (((size_t)b*NN + mm[mt])*CC1 + kt*32 + quad*8));
        float4 g0 = gp[0], g1 = gp[1];
        float hv[8] = {g0.x,g0.y,g0.z,g0.w,g1.x,g1.y,g1.z,g1.w};
        bf16x8 v;
        #pragma unroll
        for (int j = 0; j < 8; ++j) {
          float t = fmaf(dz[mt], wzs[kt][j],
                    fmaf(dy[mt], wys[kt][j],
                    fmaf(dx[mt], wxs[kt][j], shj[kt][j])));
          float h = fmaf(hv[j], scj[kt][j], t);
          v[j] = (__bf16)fmaxf(h, 0.f);
        }
        Af[mt][kt] = v;
      }
    float mx[8];
    #pragma unroll
    for (int nt = 0; nt < 8; ++nt) mx[nt] = -3.0e38f;
    #pragma unroll
    for (int mt = 0; mt < 2; ++mt) {
      f32x4 acc[8];
      #pragma unroll
      for (int nt = 0; nt < 8; ++nt) {
        f32x4 a = {0.f, 0.f, 0.f, 0.f};
        a = __builtin_amdgcn_mfma_f32_16x16x32_bf16(Af[mt][0], Bf[0][nt], a, 0, 0, 0);
        a = __builtin_amdgcn_mfma_f32_16x16x32_bf16(Af[mt][1], Bf[1][nt], a, 0, 0, 0);
        acc[nt] = a;
      }
      #pragma unroll
      for (int nt = 0; nt < 8; ++nt)
        #pragma unroll
        for (int r = 0; r < 4; ++r) {
          float v = acc[nt][r];
          ssum[nt] += v; ssq[nt] = fmaf(v, v, ssq[nt]);
          mx[nt] = fmaxf(mx[nt], v);
        }
    }
    #pragma unroll
    for (int nt = 0; nt < 8; ++nt) {
      float m = mx[nt];
      m = fmaxf(m, __shfl_xor(m, 16, 64));
      m = fmaxf(m, __shfl_xor(m, 32, 64));
      if ((nt & 3) == quad)
        out_nf[(size_t)site*CC2 + nt*16 + col] = m;   // pre-BN pooled
    }
  }
  #pragma unroll
  for (int nt = 0; nt < 8; ++nt) {
    float s = ssum[nt];
    s += __shfl_xor(s, 16, 64); s += __shfl_xor(s, 32, 64);
    float q = ssq[nt];
    q += __shfl_xor(q, 16, 64); q += __shfl_xor(q, 32, 64);
    if (lane < 16) {
      atomicAdd(&red2[nt*16 + col], s);
      atomicAdd(&red2[128 + nt*16 + col], q);
    }
  }
  __syncthreads();
  unsafeAtomicAdd(&stats2[threadIdx.x], red2[threadIdx.x]);
}

// ---------------- K45: position copy + bn2/relu in place ----------------
// blocks [0,192): copy position (49152 elems); blocks [192,8384): bn2.
__global__ __launch_bounds__(256) void k45_epi(const float* __restrict__ pos,
                                               const float* __restrict__ g2,
                                               const float* __restrict__ be2,
                                               const float* __restrict__ stats2,
                                               float* __restrict__ out)
{
  int i = blockIdx.x*256 + threadIdx.x;
  if (blockIdx.x < 192) { out[i] = pos[i]; return; }
  int j = i - 192*256;
  int c = j & (CC2-1);
  const float invc = 1.0f / (float)TOTROWS;
  float mean = stats2[c] * invc;
  float var  = stats2[128 + c] * invc - mean*mean;
  float sc = rsqrtf(var + 1e-5f) * g2[c];
  float sh = be2[c] - mean * sc;
  float* out_nf = out + (size_t)BB*NN*3;
  float x = out_nf[j];
  out_nf[j] = fmaxf(fmaf(x, sc, sh), 0.f);
}

extern "C" void kernel_launch(void* const* d_in, const int* in_sizes, int n_in,
                              void* d_out, int out_size, void* d_ws, size_t ws_size,
                              hipStream_t stream) {
  const float* pos  = (const float*)d_in[0];
  const float* feat = (const float*)d_in[1];
  const float* W1   = (const float*)d_in[2];
  const float* g1   = (const float*)d_in[3];
  const float* be1  = (const float*)d_in[4];
  const float* W2   = (const float*)d_in[5];
  const float* g2   = (const float*)d_in[6];
  const float* be2  = (const float*)d_in[7];
  float* out = (float*)d_out;
  float* out_nf = out + (size_t)BB*NN*3;

  char* w = (char*)d_ws;
  int*          idx = (int*)w;                          // 2 MB @ 0
  unsigned int* Gc  = (unsigned int*)(w + 0x200000);    // 64 KB each
  int*          Gx  = (int*)(w + 0x210000);
  int*          Gy  = (int*)(w + 0x220000);
  int*          Gz  = (int*)(w + 0x230000);
  float*        A   = (float*)(w + 0x240000);           // 320
  float*        mom = A + 320;                          // 16
  float*     stats2 = mom + 16;                         // 256
  float*        sc1 = stats2 + 256;                     // 64
  float*        sh1 = sc1 + 64;                         // 64
  float*        W1s = sh1 + 64;                         // 192
  float*        g   = (float*)(w + 0x250000);           // 4 MB

  // zero Gc..Gz (256 KB) + A/mom/stats2 (contiguous after)
  hipMemsetAsync(Gc, 0, 0x40000 + (320 + 16 + 256)*sizeof(float), stream);
  k1_ball   <<<512, 256, 0, stream>>>(pos, idx);
  kP_scatter<<<512, 256, 0, stream>>>(pos, idx, Gc, Gx, Gy, Gz, mom);
  kB_g      <<<128, 256, 0, stream>>>(feat, W1, Gc, Gx, Gy, Gz, g, A);
  kS_fold   <<<1, 256, 0, stream>>>(W1, g1, be1, A, mom, sc1, sh1, W1s);
  kD_mfma   <<<1024, 256, 0, stream>>>(pos, idx, g, sc1, sh1, W1s, W2,
                                       stats2, out_nf);
  k45_epi   <<<192 + (SITES*CC2)/256, 256, 0, stream>>>(pos, g2, be2, stats2, out);
}

// Round 13
// 355.554 us; speedup vs baseline: 1.1949x; 1.1949x over previous
//
#include <hip/hip_runtime.h>
#include <hip/hip_bf16.h>

// LocalAggregation: B=8, N=2048, K=32, D=64, C1=64, C2=128, R=0.15, EPS=1e-5
// f32 storage, bf16-ified values.
// Factored stats1 (validated R7-R12):
//   h1[row,c] = g[m,c] + dx*wx[c]+dy*wy[c]+dz*wz[c],  g = feat @ W1[3:]
//   sum1[c]   = SUM_m cnt[m] g[m,c] + wx M1x + wy M1y + wz M1z
//   sumsq1[c] = SUM_m cnt g^2 + 2(wx A3x + wy A3y + wz A3z) + quadratic moments
// R13: kP DELETED — scatter fused into k1. At accept time m = step*64+lane is
//   distinct per lane (2 lanes/bank -> conflict-free ds_add_u32), dx/dy/dz are
//   already in registers. u32 fixed-point 2^-21 (validated R12). Flush = plain
//   per-block partial stores (R11's proven path; R12 showed contended global
//   atomics cost ~170 us). kR sums 32 partials/batch -> f32 cnt/DX/DY/DZ.
//   kD remains R8 ((256,2); (256,4) spilled). k1 = 256 blocks x 64 queries.
// gamma2>0 => max-pool commutes with bn2+relu (k45).

#define BB 8
#define NN 2048
#define KK 32
#define DD 64
#define CC1 64
#define CC2 128
#define TOTROWS (BB*NN*KK) // 524288
#define SITES (BB*NN)      // 16384

typedef __bf16 bf16x8 __attribute__((ext_vector_type(8)));
typedef float  f32x4  __attribute__((ext_vector_type(4)));

__device__ __forceinline__ void lds_add(float* p, float v) {
  __hip_atomic_fetch_add(p, v, __ATOMIC_RELAXED, __HIP_MEMORY_SCOPE_WORKGROUP);
}

// ---------------- K1: ball query + fused scatter + moments ----------------
// 256 blocks x 256 thr; block = (batch, 64-query group), wave = 16 queries.
// Selector arithmetic identical to the round-4..12 PASSING versions.
__global__ __launch_bounds__(256) void k1_ball(
    const float* __restrict__ pos, int* __restrict__ idx,
    unsigned int* __restrict__ Pc, int* __restrict__ Px,
    int* __restrict__ Py, int* __restrict__ Pz,
    float* __restrict__ mom)
{
  __shared__ float4 P[NN];                 // 32 KB: x,y,z,S
  __shared__ unsigned int Sc[NN];          // 8 KB
  __shared__ int Sx[NN], Sy[NN], Sz[NN];   // 24 KB
  const int b = blockIdx.x >> 5;
  const int qbase = (blockIdx.x & 31) * 64;
  for (int i = threadIdx.x; i < NN; i += 256) {
    const float* p = pos + ((size_t)b*NN + i)*3;
    float x = p[0], y = p[1], z = p[2];
    float s = __fadd_rn(__fadd_rn(__fmul_rn(x,x), __fmul_rn(y,y)), __fmul_rn(z,z));
    P[i] = make_float4(x, y, z, s);
    Sc[i] = 0u; Sx[i] = 0; Sy[i] = 0; Sz[i] = 0;
  }
  __syncthreads();
  const int wave = threadIdx.x >> 6, lane = threadIdx.x & 63;
  const float R2 = (float)(0.15 * 0.15);
  const float FS = 2097152.0f;             // 2^21
  const unsigned long long lt = (lane == 63) ? 0x7fffffffffffffffull
                                             : ((1ull << lane) - 1ull);
  float m1x=0.f,m1y=0.f,m1z=0.f,mxx=0.f,myy=0.f,mzz=0.f,mxy=0.f,mxz=0.f,myz=0.f;
  for (int qi = wave; qi < 64; qi += 4) {
    const int q = qbase + qi;
    const float4 Q = P[q];
    int* ip = idx + ((size_t)b*NN + q)*KK;
    int cnt = 0, first = -1;
    for (int step = 0; step < 32; ++step) {
      const int m = step*64 + lane;
      float4 p = P[m];
      float d = __fmul_rn(Q.x, p.x);
      d = fmaf(Q.y, p.y, d);
      d = fmaf(Q.z, p.z, d);
      float sq = __fsub_rn(__fadd_rn(Q.w, p.w), __fmul_rn(2.0f, d));
      bool in = !(sq > R2);
      unsigned long long mask = __ballot(in);
      if (first < 0 && mask) first = step*64 + (int)__builtin_ctzll(mask);
      int dst = cnt + (int)__popcll(mask & lt);
      if (in && dst < KK) {
        ip[dst] = m;
        float dx = p.x - Q.x, dy = p.y - Q.y, dz = p.z - Q.z;
        atomicAdd(&Sc[m], 1u);   // conflict-free: m%32 = lane%32, 2 lanes/bank
        atomicAdd((unsigned int*)&Sx[m], (unsigned int)__float2int_rn(dx*FS));
        atomicAdd((unsigned int*)&Sy[m], (unsigned int)__float2int_rn(dy*FS));
        atomicAdd((unsigned int*)&Sz[m], (unsigned int)__float2int_rn(dz*FS));
        m1x += dx; m1y += dy; m1z += dz;
        mxx = fmaf(dx,dx,mxx); myy = fmaf(dy,dy,myy); mzz = fmaf(dz,dz,mzz);
        mxy = fmaf(dx,dy,mxy); mxz = fmaf(dx,dz,mxz); myz = fmaf(dy,dz,myz);
      }
      cnt += (int)__popcll(mask);
      if (cnt >= KK) break;
    }
    if (lane >= cnt && lane < KK) ip[lane] = first;  // cnt>=1 (self in ball)
    int wt = KK - cnt;
    if (wt > 0 && lane == 0) {             // padding rows: wt copies of 'first'
      float4 pf = P[first];
      float dx0 = pf.x - Q.x, dy0 = pf.y - Q.y, dz0 = pf.z - Q.z;
      float w = (float)wt;
      atomicAdd(&Sc[first], (unsigned int)wt);
      atomicAdd((unsigned int*)&Sx[first], (unsigned int)(wt*__float2int_rn(dx0*FS)));
      atomicAdd((unsigned int*)&Sy[first], (unsigned int)(wt*__float2int_rn(dy0*FS)));
      atomicAdd((unsigned int*)&Sz[first], (unsigned int)(wt*__float2int_rn(dz0*FS)));
      m1x += w*dx0; m1y += w*dy0; m1z += w*dz0;
      mxx = fmaf(w*dx0,dx0,mxx); myy = fmaf(w*dy0,dy0,myy); mzz = fmaf(w*dz0,dz0,mzz);
      mxy = fmaf(w*dx0,dy0,mxy); mxz = fmaf(w*dx0,dz0,mxz); myz = fmaf(w*dy0,dz0,myz);
    }
  }
  __syncthreads();
  // flush per-block u32 partials (plain coalesced stores, no atomics)
  {
    unsigned int* pc = Pc + (size_t)blockIdx.x*NN;
    int* px = Px + (size_t)blockIdx.x*NN;
    int* py = Py + (size_t)blockIdx.x*NN;
    int* pz = Pz + (size_t)blockIdx.x*NN;
    for (int i = threadIdx.x; i < NN; i += 256) {
      pc[i] = Sc[i]; px[i] = Sx[i]; py[i] = Sy[i]; pz[i] = Sz[i];
    }
  }
  float vals[9] = {m1x,m1y,m1z,mxx,myy,mzz,mxy,mxz,myz};
  #pragma unroll
  for (int i = 0; i < 9; ++i) {
    float v = vals[i];
    #pragma unroll
    for (int s = 1; s < 64; s <<= 1) v += __shfl_xor(v, s, 64);
    if (lane == 0) unsafeAtomicAdd(&mom[i], v);
  }
}

// ---------------- KR: reduce 32 partials/batch -> f32 cnt/DXa/DYa/DZa ----------------
// 256 blocks x 256 thr; i in [0,65536): a = array, j = b*2048+m.
// i32 modular accumulation is exact (true totals fit in i32).
__global__ __launch_bounds__(256) void kR_reduce(
    const unsigned int* __restrict__ Pc, const int* __restrict__ Px,
    const int* __restrict__ Py, const int* __restrict__ Pz,
    float* __restrict__ cnt, float* __restrict__ DXa,
    float* __restrict__ DYa, float* __restrict__ DZa)
{
  const float IS = 4.76837158203125e-7f;   // 2^-21
  int i = blockIdx.x*256 + threadIdx.x;
  int a = i >> 14;              // 0..3
  int j = i & 16383;            // b*2048 + m
  int b = j >> 11, m = j & (NN-1);
  if (a == 0) {
    unsigned int s = 0u;
    #pragma unroll 4
    for (int sl = 0; sl < 32; ++sl) s += Pc[(size_t)(b*32 + sl)*NN + m];
    cnt[j] = (float)s;
  } else {
    const int* P = (a == 1) ? Px : (a == 2) ? Py : Pz;
    int s = 0;
    #pragma unroll 4
    for (int sl = 0; sl < 32; ++sl) s += P[(size_t)(b*32 + sl)*NN + m];
    float v = (float)s * IS;
    float* O = (a == 1) ? DXa : (a == 2) ? DYa : DZa;
    O[j] = v;
  }
}

// ---------------- KB: g = feat @ W1[3:] via MFMA, fused A-sums ----------------
// 128 blocks x 256 thr -> 512 waves x 2 M-tiles (16 rows each).
// A layout: [0:64) Sum cnt*g, [64:128) Sum cnt*g^2, [128:192) Sum g*DX,
//           [192:256) Sum g*DY, [256:320) Sum g*DZ
__global__ __launch_bounds__(256) void kB_g(const float* __restrict__ feat,
                                            const float* __restrict__ W1,
                                            const float* __restrict__ cnt,
                                            const float* __restrict__ DXa,
                                            const float* __restrict__ DYa,
                                            const float* __restrict__ DZa,
                                            float* __restrict__ g,
                                            float* __restrict__ A)
{
  __shared__ float red[320];
  for (int i = threadIdx.x; i < 320; i += 256) red[i] = 0.f;
  __syncthreads();
  const int lane = threadIdx.x & 63;
  const int quad = lane >> 4;
  const int col  = lane & 15;
  const int gw = (blockIdx.x*256 + threadIdx.x) >> 6;   // 0..511

  bf16x8 Bf[2][4];
  #pragma unroll
  for (int kt = 0; kt < 2; ++kt)
    #pragma unroll
    for (int nt = 0; nt < 4; ++nt) {
      bf16x8 v;
      #pragma unroll
      for (int j = 0; j < 8; ++j)
        v[j] = (__bf16)W1[(3 + kt*32 + quad*8 + j)*CC1 + nt*16 + col];
      Bf[kt][nt] = v;
    }
  float a1[4], a2[4], a3[4], a4[4], a5[4];
  #pragma unroll
  for (int nt = 0; nt < 4; ++nt) { a1[nt]=0.f; a2[nt]=0.f; a3[nt]=0.f; a4[nt]=0.f; a5[nt]=0.f; }

  for (int t = 0; t < 2; ++t) {
    const int row0 = (gw*2 + t) * 16;
    bf16x8 Af[2];
    #pragma unroll
    for (int kt = 0; kt < 2; ++kt) {
      const float4* fp =
        (const float4*)(feat + (size_t)(row0 + col)*DD + kt*32 + quad*8);
      float4 f0 = fp[0], f1 = fp[1];
      float fv[8] = {f0.x,f0.y,f0.z,f0.w,f1.x,f1.y,f1.z,f1.w};
      bf16x8 v;
      #pragma unroll
      for (int j = 0; j < 8; ++j) v[j] = (__bf16)fv[j];
      Af[kt] = v;
    }
    float cw[4], dxw[4], dyw[4], dzw[4];
    #pragma unroll
    for (int r = 0; r < 4; ++r) {
      int row = row0 + quad*4 + r;
      cw[r] = cnt[row]; dxw[r] = DXa[row]; dyw[r] = DYa[row]; dzw[r] = DZa[row];
    }
    #pragma unroll
    for (int nt = 0; nt < 4; ++nt) {
      f32x4 a = {0.f, 0.f, 0.f, 0.f};
      a = __builtin_amdgcn_mfma_f32_16x16x32_bf16(Af[0], Bf[0][nt], a, 0, 0, 0);
      a = __builtin_amdgcn_mfma_f32_16x16x32_bf16(Af[1], Bf[1][nt], a, 0, 0, 0);
      #pragma unroll
      for (int r = 0; r < 4; ++r) {
        float v = a[r];
        g[(size_t)(row0 + quad*4 + r)*CC1 + nt*16 + col] = v;
        float cv = cw[r]*v;
        a1[nt] += cv; a2[nt] = fmaf(cv, v, a2[nt]);
        a3[nt] = fmaf(dxw[r], v, a3[nt]);
        a4[nt] = fmaf(dyw[r], v, a4[nt]);
        a5[nt] = fmaf(dzw[r], v, a5[nt]);
      }
    }
  }
  #pragma unroll
  for (int nt = 0; nt < 4; ++nt) {
    float v1=a1[nt], v2=a2[nt], v3=a3[nt], v4=a4[nt], v5=a5[nt];
    v1 += __shfl_xor(v1,16,64); v1 += __shfl_xor(v1,32,64);
    v2 += __shfl_xor(v2,16,64); v2 += __shfl_xor(v2,32,64);
    v3 += __shfl_xor(v3,16,64); v3 += __shfl_xor(v3,32,64);
    v4 += __shfl_xor(v4,16,64); v4 += __shfl_xor(v4,32,64);
    v5 += __shfl_xor(v5,16,64); v5 += __shfl_xor(v5,32,64);
    if (quad == 0) {
      int ch = nt*16 + col;
      lds_add(&red[ch], v1);
      lds_add(&red[64+ch], v2);
      lds_add(&red[128+ch], v3);
      lds_add(&red[192+ch], v4);
      lds_add(&red[256+ch], v5);
    }
  }
  __syncthreads();
  for (int i = threadIdx.x; i < 320; i += 256) unsafeAtomicAdd(&A[i], red[i]);
}

// ---------------- KS: assemble stats1 -> sc1, sh1, W1s ----------------
__global__ __launch_bounds__(256) void kS_fold(
    const float* __restrict__ W1, const float* __restrict__ gamma1,
    const float* __restrict__ beta1, const float* __restrict__ A,
    const float* __restrict__ mom,
    float* __restrict__ sc1, float* __restrict__ sh1, float* __restrict__ W1s)
{
  int c = threadIdx.x;
  if (c >= CC1) return;
  float wx = W1[c], wy = W1[CC1+c], wz = W1[2*CC1+c];
  float A1 = A[c], A2 = A[64+c], A3x = A[128+c], A3y = A[192+c], A3z = A[256+c];
  float sum1 = A1 + wx*mom[0] + wy*mom[1] + wz*mom[2];
  float ss = A2 + 2.f*(wx*A3x + wy*A3y + wz*A3z)
           + wx*wx*mom[3] + wy*wy*mom[4] + wz*wz*mom[5]
           + 2.f*(wx*wy*mom[6] + wx*wz*mom[7] + wy*wz*mom[8]);
  const float invN = 1.0f / (float)TOTROWS;
  float mean = sum1 * invN;
  float var  = ss * invN - mean*mean;
  float sc = rsqrtf(var + 1e-5f) * gamma1[c];
  float sh = beta1[c] - mean * sc;
  sc1[c] = sc; sh1[c] = sh;
  W1s[c] = wx*sc; W1s[64+c] = wy*sc; W1s[128+c] = wz*sc;
}

// ---------------- KD: MFMA main pass (BN1 inline) — R8 version ----------------
// 1024 blocks -> 4096 waves x 4 sites. Per site A1(32x64 bf16) @ W2(64x128).
// a = relu(g*sc + dx*wxs + dy*wys + dz*wzs + sh).
__global__ __launch_bounds__(256, 2) void kD_mfma(
    const float* __restrict__ pos, const int* __restrict__ idx,
    const float* __restrict__ g, const float* __restrict__ sc1,
    const float* __restrict__ sh1, const float* __restrict__ W1s,
    const float* __restrict__ W2,
    float* __restrict__ stats2, float* __restrict__ out_nf)
{
  __shared__ float red2[256];
  red2[threadIdx.x] = 0.f;
  __syncthreads();
  const int lane = threadIdx.x & 63;
  const int quad = lane >> 4;
  const int col  = lane & 15;
  const int gw = (blockIdx.x*256 + threadIdx.x) >> 6;

  bf16x8 Bf[2][8];
  #pragma unroll
  for (int kt = 0; kt < 2; ++kt)
    #pragma unroll
    for (int nt = 0; nt < 8; ++nt) {
      bf16x8 v;
      #pragma unroll
      for (int j = 0; j < 8; ++j)
        v[j] = (__bf16)W2[(kt*32 + quad*8 + j)*CC2 + nt*16 + col];
      Bf[kt][nt] = v;
    }
  float wxs[2][8], wys[2][8], wzs[2][8], scj[2][8], shj[2][8];
  #pragma unroll
  for (int kt = 0; kt < 2; ++kt)
    #pragma unroll
    for (int j = 0; j < 8; ++j) {
      int c = kt*32 + quad*8 + j;
      wxs[kt][j] = W1s[c]; wys[kt][j] = W1s[64+c]; wzs[kt][j] = W1s[128+c];
      scj[kt][j] = sc1[c]; shj[kt][j] = sh1[c];
    }
  float ssum[8], ssq[8];
  #pragma unroll
  for (int nt = 0; nt < 8; ++nt) { ssum[nt] = 0.f; ssq[nt] = 0.f; }

  for (int si = 0; si < 4; ++si) {
    const int site = gw*4 + si;
    const int b = site >> 11;
    const float* pc = pos + (size_t)site*3;
    const float cx = pc[0], cy = pc[1], cz = pc[2];
    int mm[2]; float dx[2], dy[2], dz[2];
    #pragma unroll
    for (int mt = 0; mt < 2; ++mt) {
      mm[mt] = idx[site*KK + mt*16 + col];
      const float* pm = pos + ((size_t)b*NN + mm[mt])*3;
      dx[mt] = pm[0]-cx; dy[mt] = pm[1]-cy; dz[mt] = pm[2]-cz;
    }
    bf16x8 Af[2][2];
    #pragma unroll
    for (int mt = 0; mt < 2; ++mt)
      #pragma unroll
      for (int kt = 0; kt < 2; ++kt) {
        const float4* gp =
          (const float4*)(g + (((size_t)b*NN + mm[mt])*CC1 + kt*32 + quad*8));
        float4 g0 = gp[0], g1 = gp[1];
        float hv[8] = {g0.x,g0.y,g0.z,g0.w,g1.x,g1.y,g1.z,g1.w};
        bf16x8 v;
        #pragma unroll
        for (int j = 0; j < 8; ++j) {
          float t = fmaf(dz[mt], wzs[kt][j],
                    fmaf(dy[mt], wys[kt][j],
                    fmaf(dx[mt], wxs[kt][j], shj[kt][j])));
          float h = fmaf(hv[j], scj[kt][j], t);
          v[j] = (__bf16)fmaxf(h, 0.f);
        }
        Af[mt][kt] = v;
      }
    float mx[8];
    #pragma unroll
    for (int nt = 0; nt < 8; ++nt) mx[nt] = -3.0e38f;
    #pragma unroll
    for (int mt = 0; mt < 2; ++mt) {
      f32x4 acc[8];
      #pragma unroll
      for (int nt = 0; nt < 8; ++nt) {
        f32x4 a = {0.f, 0.f, 0.f, 0.f};
        a = __builtin_amdgcn_mfma_f32_16x16x32_bf16(Af[mt][0], Bf[0][nt], a, 0, 0, 0);
        a = __builtin_amdgcn_mfma_f32_16x16x32_bf16(Af[mt][1], Bf[1][nt], a, 0, 0, 0);
        acc[nt] = a;
      }
      #pragma unroll
      for (int nt = 0; nt < 8; ++nt)
        #pragma unroll
        for (int r = 0; r < 4; ++r) {
          float v = acc[nt][r];
          ssum[nt] += v; ssq[nt] = fmaf(v, v, ssq[nt]);
          mx[nt] = fmaxf(mx[nt], v);
        }
    }
    #pragma unroll
    for (int nt = 0; nt < 8; ++nt) {
      float m = mx[nt];
      m = fmaxf(m, __shfl_xor(m, 16, 64));
      m = fmaxf(m, __shfl_xor(m, 32, 64));
      if ((nt & 3) == quad)
        out_nf[(size_t)site*CC2 + nt*16 + col] = m;   // pre-BN pooled
    }
  }
  #pragma unroll
  for (int nt = 0; nt < 8; ++nt) {
    float s = ssum[nt];
    s += __shfl_xor(s, 16, 64); s += __shfl_xor(s, 32, 64);
    float q = ssq[nt];
    q += __shfl_xor(q, 16, 64); q += __shfl_xor(q, 32, 64);
    if (lane < 16) {
      atomicAdd(&red2[nt*16 + col], s);
      atomicAdd(&red2[128 + nt*16 + col], q);
    }
  }
  __syncthreads();
  unsafeAtomicAdd(&stats2[threadIdx.x], red2[threadIdx.x]);
}

// ---------------- K45: position copy + bn2/relu in place ----------------
// blocks [0,192): copy position (49152 elems); blocks [192,8384): bn2.
__global__ __launch_bounds__(256) void k45_epi(const float* __restrict__ pos,
                                               const float* __restrict__ g2,
                                               const float* __restrict__ be2,
                                               const float* __restrict__ stats2,
                                               float* __restrict__ out)
{
  int i = blockIdx.x*256 + threadIdx.x;
  if (blockIdx.x < 192) { out[i] = pos[i]; return; }
  int j = i - 192*256;
  int c = j & (CC2-1);
  const float invc = 1.0f / (float)TOTROWS;
  float mean = stats2[c] * invc;
  float var  = stats2[128 + c] * invc - mean*mean;
  float sc = rsqrtf(var + 1e-5f) * g2[c];
  float sh = be2[c] - mean * sc;
  float* out_nf = out + (size_t)BB*NN*3;
  float x = out_nf[j];
  out_nf[j] = fmaxf(fmaf(x, sc, sh), 0.f);
}

extern "C" void kernel_launch(void* const* d_in, const int* in_sizes, int n_in,
                              void* d_out, int out_size, void* d_ws, size_t ws_size,
                              hipStream_t stream) {
  const float* pos  = (const float*)d_in[0];
  const float* feat = (const float*)d_in[1];
  const float* W1   = (const float*)d_in[2];
  const float* g1   = (const float*)d_in[3];
  const float* be1  = (const float*)d_in[4];
  const float* W2   = (const float*)d_in[5];
  const float* g2   = (const float*)d_in[6];
  const float* be2  = (const float*)d_in[7];
  float* out = (float*)d_out;
  float* out_nf = out + (size_t)BB*NN*3;

  char* w = (char*)d_ws;
  int*          idx = (int*)w;                          // 2 MB @ 0
  float*        A   = (float*)(w + 0x200000);           // 320
  float*        mom = A + 320;                          // 16
  float*     stats2 = mom + 16;                         // 256
  float*        sc1 = stats2 + 256;                     // 64
  float*        sh1 = sc1 + 64;                         // 64
  float*        W1s = sh1 + 64;                         // 192
  float*        cnt = (float*)(w + 0x210000);           // 64 KB each (f32)
  float*        DXa = cnt + SITES;
  float*        DYa = DXa + SITES;
  float*        DZa = DYa + SITES;
  float*        g   = (float*)(w + 0x250000);           // 4 MB
  unsigned int* Pc  = (unsigned int*)(w + 0x650000);    // 256*2048*4B = 2 MB each
  int*          Px  = (int*)(w + 0x850000);
  int*          Py  = (int*)(w + 0xA50000);
  int*          Pz  = (int*)(w + 0xC50000);             // ends 0xE50000 (~14.3 MB)

  hipMemsetAsync(A, 0, (320 + 16 + 256)*sizeof(float), stream);
  k1_ball  <<<256, 256, 0, stream>>>(pos, idx, Pc, Px, Py, Pz, mom);
  kR_reduce<<<256, 256, 0, stream>>>(Pc, Px, Py, Pz, cnt, DXa, DYa, DZa);
  kB_g     <<<128, 256, 0, stream>>>(feat, W1, cnt, DXa, DYa, DZa, g, A);
  kS_fold  <<<1, 256, 0, stream>>>(W1, g1, be1, A, mom, sc1, sh1, W1s);
  kD_mfma  <<<1024, 256, 0, stream>>>(pos, idx, g, sc1, sh1, W1s, W2,
                                      stats2, out_nf);
  k45_epi  <<<192 + (SITES*CC2)/256, 256, 0, stream>>>(pos, g2, be2, stats2, out);
}